// Round 4
// baseline (20949.049 us; speedup 1.0000x reference)
//
#include <hip/hip_runtime.h>
#include <hip/hip_bf16.h>

// theta_solver on MI355X — R4: R3's software-pipelined eval + R1's fp32 y-state.
// Per f-eval (4 HID-chunks of 128): GEMM1(c+1) MFMA stream fused with
// tanh(c)+scatter (VALU+LDS-write) in one loop body -> VALU hides under MFMA.
// Hc double-buffered: 4 barriers/eval + 1 writeback barrier (was 9 in R1).
// y-state fp32 in registers (bf16 state in R3 cost +0.22 absmax -> FAILED;
// fp32 is precision-proven at 0.031). Final step writes out in fp32 directly.

typedef short short8 __attribute__((ext_vector_type(8)));
typedef float floatx4 __attribute__((ext_vector_type(4)));

#define MFMA(a, b, c) __builtin_amdgcn_mfma_f32_16x16x32_bf16((a), (b), (c), 0, 0, 0)

__device__ __forceinline__ short f2bf(float f) {
    __hip_bfloat16 h = __float2bfloat16(f);
    return *reinterpret_cast<short*>(&h);
}
__device__ __forceinline__ float fast_tanh(float x) {
    // tanh(x) = 1 - 2/(1+e^{2x}); exact identity, graceful at +/-inf.
    float e = __expf(2.0f * x);
    return 1.0f - 2.0f * __builtin_amdgcn_rcpf(1.0f + e);
}

// ---------------------------------------------------------------------------
// Weight repack (unchanged from R1): W1 [256x512] f32 -> W1p bf16 B-frags.
//   bi = ct*8 + s; W1p[(bi*64+lane)*8+j] = bf16(W1[(32s+8q+j)*512 + 16ct+c])
// W2 [512x256] f32 -> W2p, bi = ct*16 + s.
// ---------------------------------------------------------------------------
__global__ void repack_weights(const float* __restrict__ W1,
                               const float* __restrict__ W2,
                               short* __restrict__ W1p,
                               short* __restrict__ W2p) {
    int t = blockIdx.x * blockDim.x + threadIdx.x;  // 0..32767
    int lane = t & 63;
    int q = lane >> 4, c = lane & 15;
    if (t < 16384) {
        int s = (t >> 6) & 7;
        int ct = t >> 9;
        short8 v;
#pragma unroll
        for (int j = 0; j < 8; ++j) v[j] = f2bf(W1[(32 * s + 8 * q + j) * 512 + 16 * ct + c]);
        *reinterpret_cast<short8*>(&W1p[t * 8]) = v;
    } else {
        int t2 = t - 16384;
        int s = (t2 >> 6) & 15;
        int ct = t2 >> 10;
        short8 v;
#pragma unroll
        for (int j = 0; j < 8; ++j) v[j] = f2bf(W2[(32 * s + 8 * q + j) * 256 + 16 * ct + c]);
        *reinterpret_cast<short8*>(&W2p[t2 * 8]) = v;
    }
}

// ---------------------------------------------------------------------------
// Phase 1: GEMM1 chunk CHUNK -> g (if DO_G1), fused with tanh(gp)->HcDst (if
// FUSE). Fusing puts the tanh VALU stream next to the MFMA stream.
// ---------------------------------------------------------------------------
template <int CHUNK, bool DO_G1, bool FUSE>
__device__ __forceinline__ void g1_tanh(
    const short* __restrict__ W1p, const float* __restrict__ b1r,
    const short* __restrict__ Yb, short* __restrict__ HcDst,
    int w, int lane, int q, int c,
    floatx4 (&g)[4][2], floatx4 (&gp)[4][2]) {
    const short* w1base = W1p + (8 * CHUNK + 2 * w) * 4096 + lane * 8;
    if (DO_G1) {
#pragma unroll
        for (int nt = 0; nt < 2; ++nt) {
            float bv = b1r[CHUNK * 2 + nt];
            floatx4 g0 = {bv, bv, bv, bv};
#pragma unroll
            for (int mt = 0; mt < 4; ++mt) g[mt][nt] = g0;
        }
    }
#pragma unroll
    for (int s = 0; s < 8; ++s) {
        if (DO_G1) {
            short8 a0 = *reinterpret_cast<const short8*>(&Yb[((0 * 8 + s) * 64 + lane) * 8]);
            short8 a1 = *reinterpret_cast<const short8*>(&Yb[((1 * 8 + s) * 64 + lane) * 8]);
            short8 a2 = *reinterpret_cast<const short8*>(&Yb[((2 * 8 + s) * 64 + lane) * 8]);
            short8 a3 = *reinterpret_cast<const short8*>(&Yb[((3 * 8 + s) * 64 + lane) * 8]);
            short8 wb0 = *reinterpret_cast<const short8*>(&w1base[(0 * 8 + s) * 512]);
            short8 wb1 = *reinterpret_cast<const short8*>(&w1base[(1 * 8 + s) * 512]);
            g[0][0] = MFMA(a0, wb0, g[0][0]);
            g[1][0] = MFMA(a1, wb0, g[1][0]);
            g[2][0] = MFMA(a2, wb0, g[2][0]);
            g[3][0] = MFMA(a3, wb0, g[3][0]);
            g[0][1] = MFMA(a0, wb1, g[0][1]);
            g[1][1] = MFMA(a1, wb1, g[1][1]);
            g[2][1] = MFMA(a2, wb1, g[2][1]);
            g[3][1] = MFMA(a3, wb1, g[3][1]);
        }
        if (FUSE) {
            // 4 of 32 prev-chunk values per s-step: (mt = s>>1, nt = s&1)
            int mt = s >> 1, nt = s & 1;
            int lp = 4 * q + 16 * ((2 * nt + (c >> 3)) & 3);
            short* dst = &HcDst[((mt * 4 + w) * 64 + lp) * 8 + (c & 7)];
#pragma unroll
            for (int r = 0; r < 4; ++r)
                dst[8 * r] = f2bf(fast_tanh(gp[mt][nt][r]));
        }
    }
}

// ---------------------------------------------------------------------------
// Phase 2: GEMM2 partial for chunk CHUNK: facc += Hc[64x128] @ W2chunk.
// ---------------------------------------------------------------------------
template <int CHUNK>
__device__ __forceinline__ void g2(
    const short* __restrict__ W2p, const short* __restrict__ Hc,
    int w, int lane, floatx4 (&facc)[4][4]) {
    const short* w2base = W2p + (64 * w + 4 * CHUNK) * 512 + lane * 8;
#pragma unroll
    for (int ks = 0; ks < 4; ++ks) {
        short8 a0 = *reinterpret_cast<const short8*>(&Hc[((0 * 4 + ks) * 64 + lane) * 8]);
        short8 a1 = *reinterpret_cast<const short8*>(&Hc[((1 * 4 + ks) * 64 + lane) * 8]);
        short8 a2 = *reinterpret_cast<const short8*>(&Hc[((2 * 4 + ks) * 64 + lane) * 8]);
        short8 a3 = *reinterpret_cast<const short8*>(&Hc[((3 * 4 + ks) * 64 + lane) * 8]);
        short8 wb0 = *reinterpret_cast<const short8*>(&w2base[(0 * 16 + ks) * 512]);
        short8 wb1 = *reinterpret_cast<const short8*>(&w2base[(1 * 16 + ks) * 512]);
        short8 wb2 = *reinterpret_cast<const short8*>(&w2base[(2 * 16 + ks) * 512]);
        short8 wb3 = *reinterpret_cast<const short8*>(&w2base[(3 * 16 + ks) * 512]);
        facc[0][0] = MFMA(a0, wb0, facc[0][0]);
        facc[1][0] = MFMA(a1, wb0, facc[1][0]);
        facc[2][0] = MFMA(a2, wb0, facc[2][0]);
        facc[3][0] = MFMA(a3, wb0, facc[3][0]);
        facc[0][1] = MFMA(a0, wb1, facc[0][1]);
        facc[1][1] = MFMA(a1, wb1, facc[1][1]);
        facc[2][1] = MFMA(a2, wb1, facc[2][1]);
        facc[3][1] = MFMA(a3, wb1, facc[3][1]);
        facc[0][2] = MFMA(a0, wb2, facc[0][2]);
        facc[1][2] = MFMA(a1, wb2, facc[1][2]);
        facc[2][2] = MFMA(a2, wb2, facc[2][2]);
        facc[3][2] = MFMA(a3, wb2, facc[3][2]);
        facc[0][3] = MFMA(a0, wb3, facc[0][3]);
        facc[1][3] = MFMA(a1, wb3, facc[1][3]);
        facc[2][3] = MFMA(a2, wb3, facc[2][3]);
        facc[3][3] = MFMA(a3, wb3, facc[3][3]);
    }
}

// One f-eval, pipelined: tanh(chunk c) fused under GEMM1(chunk c+1);
// Hc double-buffered -> 4 barriers. Entered with Yb ready (barrier before).
__device__ __forceinline__ void eval_f(
    const short* __restrict__ W1p, const short* __restrict__ W2p,
    const float* __restrict__ b1r, const float* __restrict__ b2r,
    const short* __restrict__ Yb, short* __restrict__ Hc0, short* __restrict__ Hc1,
    int w, int lane, int q, int c, floatx4 (&facc)[4][4]) {
    floatx4 ga[4][2], gb[4][2];
#pragma unroll
    for (int nt = 0; nt < 4; ++nt) {
        float bv = b2r[nt];
        floatx4 f0 = {bv, bv, bv, bv};
#pragma unroll
        for (int mt = 0; mt < 4; ++mt) facc[mt][nt] = f0;
    }
    g1_tanh<0, true, false>(W1p, b1r, Yb, nullptr, w, lane, q, c, ga, ga);
    g1_tanh<1, true, true>(W1p, b1r, Yb, Hc0, w, lane, q, c, gb, ga);  // tanh(ga)=H0
    __syncthreads();
    g2<0>(W2p, Hc0, w, lane, facc);
    g1_tanh<2, true, true>(W1p, b1r, Yb, Hc1, w, lane, q, c, ga, gb);  // tanh(gb)=H1
    __syncthreads();
    g2<1>(W2p, Hc1, w, lane, facc);
    g1_tanh<3, true, true>(W1p, b1r, Yb, Hc0, w, lane, q, c, gb, ga);  // tanh(ga)=H2
    __syncthreads();
    g2<2>(W2p, Hc0, w, lane, facc);
    g1_tanh<0, false, true>(W1p, b1r, Yb, Hc1, w, lane, q, c, ga, gb);  // tanh(gb)=H3
    __syncthreads();
    g2<3>(W2p, Hc1, w, lane, facc);
}

__global__ __launch_bounds__(256, 2) void theta_main(
    const float* __restrict__ x,
    const float* __restrict__ b1,
    const float* __restrict__ b2,
    const short* __restrict__ W1p,
    const short* __restrict__ W2p,
    float* __restrict__ out) {
    __shared__ __align__(16) short Yb[16384];  // 64r x 256k A-frags, 32 KB
    __shared__ __align__(16) short Hc0[8192];  // 64r x 128k chunk, 16 KB
    __shared__ __align__(16) short Hc1[8192];  // double buffer, 16 KB

    const int tid = threadIdx.x;
    const int w = tid >> 6;
    const int lane = tid & 63;
    const int q = lane >> 4, c = lane & 15;
    const int row0 = blockIdx.x << 6;
    const float HT = 0.0625f;  // h*theta == h*(1-theta)

    float b1r[8], b2r[4];
#pragma unroll
    for (int k = 0; k < 8; ++k) b1r[k] = b1[128 * (k >> 1) + 32 * w + 16 * (k & 1) + c];
#pragma unroll
    for (int nt = 0; nt < 4; ++nt) b2r[nt] = b2[64 * w + 16 * nt + c];

    // y state (becomes expl during FP iters), fp32, C-layout.
    // Wave w owns cols [64w, 64w+64).
    float yv[4][4][4];
#pragma unroll
    for (int mt = 0; mt < 4; ++mt)
#pragma unroll
        for (int nt = 0; nt < 4; ++nt)
#pragma unroll
            for (int r = 0; r < 4; ++r)
                yv[mt][nt][r] = x[(row0 + 16 * mt + 4 * q + r) * 256 + 64 * w + 16 * nt + c];

    // initial Yb = bf16(x) in A-frag layout; wave w fills m-tile w
#pragma unroll
    for (int s = 0; s < 8; ++s) {
        short8 v;
#pragma unroll
        for (int j = 0; j < 8; ++j)
            v[j] = f2bf(x[(row0 + 16 * w + c) * 256 + 32 * s + 8 * q + j]);
        *reinterpret_cast<short8*>(&Yb[((w * 8 + s) * 64 + lane) * 8]) = v;
    }
    __syncthreads();

    floatx4 facc[4][4];

#pragma unroll 1
    for (int step = 0; step < 8; ++step) {
#pragma unroll 1
        for (int it = 0; it < 20; ++it) {
            eval_f(W1p, W2p, b1r, b2r, Yb, Hc0, Hc1, w, lane, q, c, facc);
            const bool upd = (it == 0) || (it == 19);   // expl update / final y
            const bool last = (it == 19);
            const bool fin = last && (step == 7);
#pragma unroll
            for (int mt = 0; mt < 4; ++mt)
#pragma unroll
                for (int nt = 0; nt < 4; ++nt) {
                    int kst = 2 * w + (nt >> 1);
                    int lp = 4 * q + 16 * ((2 * nt + (c >> 3)) & 3);
                    short* dst = &Yb[((mt * 8 + kst) * 64 + lp) * 8 + (c & 7)];
#pragma unroll
                    for (int r = 0; r < 4; ++r) {
                        float fv = facc[mt][nt][r];
                        if (upd) yv[mt][nt][r] += HT * fv;
                        float z = last ? yv[mt][nt][r] : yv[mt][nt][r] + HT * fv;
                        if (fin) {
                            out[(row0 + 16 * mt + 4 * q + r) * 256 + 64 * w + 16 * nt + c] = z;
                        } else {
                            dst[8 * r] = f2bf(z);
                        }
                    }
                }
            __syncthreads();
        }
    }
}

extern "C" void kernel_launch(void* const* d_in, const int* in_sizes, int n_in,
                              void* d_out, int out_size, void* d_ws, size_t ws_size,
                              hipStream_t stream) {
    const float* x = (const float*)d_in[0];
    const float* W1 = (const float*)d_in[1];
    const float* b1 = (const float*)d_in[2];
    const float* W2 = (const float*)d_in[3];
    const float* b2 = (const float*)d_in[4];
    float* out = (float*)d_out;

    short* W1p = (short*)d_ws;            // 256*512 bf16 = 256 KB
    short* W2p = W1p + 256 * 512;         // 512*256 bf16 = 256 KB

    repack_weights<<<dim3(128), dim3(256), 0, stream>>>(W1, W2, W1p, W2p);
    theta_main<<<dim3(1024), dim3(256), 0, stream>>>(x, b1, b2, W1p, W2p, out);
}

// Round 5
// 16984.288 us; speedup vs baseline: 1.2334x; 1.2334x over previous
//
#include <hip/hip_runtime.h>
#include <hip/hip_bf16.h>

// theta_solver on MI355X — R5: R1's structure + low-register pipelining.
// Key change vs R4 (which spilled catastrophically: ga+gb = 64 extra regs ->
// 46 GB scratch FETCH): after g1(c), tanh is applied immediately and packed
// to bf16 pairs th[8][2] (16 regs), freeing the single g buffer (32 regs) for
// chunk c+1. The LDS scatter of th(c) is fused into the NEXT phase's MFMA
// loop (g1<1> for c0, g2<c-1> for c1..c3), so all 128 b16 scatter writes per
// wave-eval issue under MFMA. Hc double-buffered -> 5 barriers/eval (R1: 9).
// y-state fp32 in registers (precision-proven: absmax 0.03125).

typedef short short8 __attribute__((ext_vector_type(8)));
typedef float floatx4 __attribute__((ext_vector_type(4)));

#define MFMA(a, b, c) __builtin_amdgcn_mfma_f32_16x16x32_bf16((a), (b), (c), 0, 0, 0)

__device__ __forceinline__ short f2bf(float f) {
    __hip_bfloat16 h = __float2bfloat16(f);
    return *reinterpret_cast<short*>(&h);
}
__device__ __forceinline__ unsigned bf_pack(float a, float b) {
    return (unsigned)(unsigned short)f2bf(a) | ((unsigned)(unsigned short)f2bf(b) << 16);
}
__device__ __forceinline__ float fast_tanh(float x) {
    // tanh(x) = 1 - 2/(1+e^{2x}); exact identity, graceful at +/-inf.
    float e = __expf(2.0f * x);
    return 1.0f - 2.0f * __builtin_amdgcn_rcpf(1.0f + e);
}

// ---------------------------------------------------------------------------
// Weight repack (unchanged from R1): W1 [256x512] f32 -> W1p bf16 B-frags.
// ---------------------------------------------------------------------------
__global__ void repack_weights(const float* __restrict__ W1,
                               const float* __restrict__ W2,
                               short* __restrict__ W1p,
                               short* __restrict__ W2p) {
    int t = blockIdx.x * blockDim.x + threadIdx.x;  // 0..32767
    int lane = t & 63;
    int q = lane >> 4, c = lane & 15;
    if (t < 16384) {
        int s = (t >> 6) & 7;
        int ct = t >> 9;
        short8 v;
#pragma unroll
        for (int j = 0; j < 8; ++j) v[j] = f2bf(W1[(32 * s + 8 * q + j) * 512 + 16 * ct + c]);
        *reinterpret_cast<short8*>(&W1p[t * 8]) = v;
    } else {
        int t2 = t - 16384;
        int s = (t2 >> 6) & 15;
        int ct = t2 >> 10;
        short8 v;
#pragma unroll
        for (int j = 0; j < 8; ++j) v[j] = f2bf(W2[(32 * s + 8 * q + j) * 256 + 16 * ct + c]);
        *reinterpret_cast<short8*>(&W2p[t2 * 8]) = v;
    }
}

// Scatter one (mt,nt) pair of packed tanh values into A-frag layout.
// Element offset = ((mt*4 + w)*64 + 4q + 16*(2nt+cbit))*8 + (c&7), r at +8r.
__device__ __forceinline__ void scat_pair(short* __restrict__ HcS, int p,
                                          int w, int q, int cbit, int c7,
                                          unsigned t0, unsigned t1) {
    int mt = p >> 1, nt = p & 1;
    short* dst = HcS + mt * 2048 + w * 512 + q * 32 + 128 * (2 * nt + cbit) + c7;
    dst[0] = (short)t0;
    dst[8] = (short)(t0 >> 16);
    dst[16] = (short)t1;
    dst[24] = (short)(t1 >> 16);
}

// tanh(g) -> packed bf16 pairs; frees g for the next chunk.
__device__ __forceinline__ void tanh_pack(const floatx4 (&g)[4][2], unsigned (&th)[8][2]) {
#pragma unroll
    for (int mt = 0; mt < 4; ++mt)
#pragma unroll
        for (int nt = 0; nt < 2; ++nt) {
            int p = mt * 2 + nt;
            th[p][0] = bf_pack(fast_tanh(g[mt][nt][0]), fast_tanh(g[mt][nt][1]));
            th[p][1] = bf_pack(fast_tanh(g[mt][nt][2]), fast_tanh(g[mt][nt][3]));
        }
}

// ---------------------------------------------------------------------------
// GEMM1 chunk -> g; optional fused scatter of th (previous chunk) into HcS.
// ---------------------------------------------------------------------------
template <int CHUNK, bool SCAT>
__device__ __forceinline__ void g1f(
    const short* __restrict__ W1p, const float* __restrict__ b1r,
    const short* __restrict__ Yb, short* __restrict__ HcS,
    int w, int lane, int q, int cbit, int c7,
    floatx4 (&g)[4][2], const unsigned (&th)[8][2]) {
    const short* w1base = W1p + (8 * CHUNK + 2 * w) * 4096 + lane * 8;
#pragma unroll
    for (int nt = 0; nt < 2; ++nt) {
        float bv = b1r[CHUNK * 2 + nt];
        floatx4 g0 = {bv, bv, bv, bv};
#pragma unroll
        for (int mt = 0; mt < 4; ++mt) g[mt][nt] = g0;
    }
#pragma unroll
    for (int s = 0; s < 8; ++s) {
        short8 a0 = *reinterpret_cast<const short8*>(&Yb[((0 * 8 + s) * 64 + lane) * 8]);
        short8 a1 = *reinterpret_cast<const short8*>(&Yb[((1 * 8 + s) * 64 + lane) * 8]);
        short8 a2 = *reinterpret_cast<const short8*>(&Yb[((2 * 8 + s) * 64 + lane) * 8]);
        short8 a3 = *reinterpret_cast<const short8*>(&Yb[((3 * 8 + s) * 64 + lane) * 8]);
        short8 wb0 = *reinterpret_cast<const short8*>(&w1base[(0 * 8 + s) * 512]);
        short8 wb1 = *reinterpret_cast<const short8*>(&w1base[(1 * 8 + s) * 512]);
        g[0][0] = MFMA(a0, wb0, g[0][0]);
        g[1][0] = MFMA(a1, wb0, g[1][0]);
        g[2][0] = MFMA(a2, wb0, g[2][0]);
        g[3][0] = MFMA(a3, wb0, g[3][0]);
        g[0][1] = MFMA(a0, wb1, g[0][1]);
        g[1][1] = MFMA(a1, wb1, g[1][1]);
        g[2][1] = MFMA(a2, wb1, g[2][1]);
        g[3][1] = MFMA(a3, wb1, g[3][1]);
        if (SCAT) scat_pair(HcS, s, w, q, cbit, c7, th[s][0], th[s][1]);
    }
}

// ---------------------------------------------------------------------------
// GEMM2 partial for chunk CHUNK: facc += Hc[64x128] @ W2chunk; optional fused
// scatter of th (next chunk's H) into HcS.
// ---------------------------------------------------------------------------
template <int CHUNK, bool SCAT>
__device__ __forceinline__ void g2f(
    const short* __restrict__ W2p, const short* __restrict__ Hc,
    short* __restrict__ HcS, int w, int lane, int q, int cbit, int c7,
    floatx4 (&facc)[4][4], const unsigned (&th)[8][2]) {
    const short* w2base = W2p + (64 * w + 4 * CHUNK) * 512 + lane * 8;
#pragma unroll
    for (int ks = 0; ks < 4; ++ks) {
        short8 a0 = *reinterpret_cast<const short8*>(&Hc[((0 * 4 + ks) * 64 + lane) * 8]);
        short8 a1 = *reinterpret_cast<const short8*>(&Hc[((1 * 4 + ks) * 64 + lane) * 8]);
        short8 a2 = *reinterpret_cast<const short8*>(&Hc[((2 * 4 + ks) * 64 + lane) * 8]);
        short8 a3 = *reinterpret_cast<const short8*>(&Hc[((3 * 4 + ks) * 64 + lane) * 8]);
        short8 wb0 = *reinterpret_cast<const short8*>(&w2base[(0 * 16 + ks) * 512]);
        short8 wb1 = *reinterpret_cast<const short8*>(&w2base[(1 * 16 + ks) * 512]);
        short8 wb2 = *reinterpret_cast<const short8*>(&w2base[(2 * 16 + ks) * 512]);
        short8 wb3 = *reinterpret_cast<const short8*>(&w2base[(3 * 16 + ks) * 512]);
        facc[0][0] = MFMA(a0, wb0, facc[0][0]);
        facc[1][0] = MFMA(a1, wb0, facc[1][0]);
        facc[2][0] = MFMA(a2, wb0, facc[2][0]);
        facc[3][0] = MFMA(a3, wb0, facc[3][0]);
        facc[0][1] = MFMA(a0, wb1, facc[0][1]);
        facc[1][1] = MFMA(a1, wb1, facc[1][1]);
        facc[2][1] = MFMA(a2, wb1, facc[2][1]);
        facc[3][1] = MFMA(a3, wb1, facc[3][1]);
        facc[0][2] = MFMA(a0, wb2, facc[0][2]);
        facc[1][2] = MFMA(a1, wb2, facc[1][2]);
        facc[2][2] = MFMA(a2, wb2, facc[2][2]);
        facc[3][2] = MFMA(a3, wb2, facc[3][2]);
        facc[0][3] = MFMA(a0, wb3, facc[0][3]);
        facc[1][3] = MFMA(a1, wb3, facc[1][3]);
        facc[2][3] = MFMA(a2, wb3, facc[2][3]);
        facc[3][3] = MFMA(a3, wb3, facc[3][3]);
        if (SCAT) {
            scat_pair(HcS, 2 * ks, w, q, cbit, c7, th[2 * ks][0], th[2 * ks][1]);
            scat_pair(HcS, 2 * ks + 1, w, q, cbit, c7, th[2 * ks + 1][0], th[2 * ks + 1][1]);
        }
    }
}

// One f-eval. Schedule (5 barriers):
//   g1<0>; tanh(c0); g1<1>||scat(c0)->Hc0; tanh(c1); B;
//   g2<0>(Hc0)||scat(c1)->Hc1; g1<2>; tanh(c2); B;
//   g2<1>(Hc1)||scat(c2)->Hc0; g1<3>; tanh(c3); B;
//   g2<2>(Hc0)||scat(c3)->Hc1; B; g2<3>(Hc1); [writeback; B in caller]
__device__ __forceinline__ void eval_f(
    const short* __restrict__ W1p, const short* __restrict__ W2p,
    const float* __restrict__ b1r, const float* __restrict__ b2r,
    const short* __restrict__ Yb, short* __restrict__ Hc0, short* __restrict__ Hc1,
    int w, int lane, int q, int cbit, int c7, floatx4 (&facc)[4][4]) {
    floatx4 g[4][2];
    unsigned th[8][2];
#pragma unroll
    for (int nt = 0; nt < 4; ++nt) {
        float bv = b2r[nt];
        floatx4 f0 = {bv, bv, bv, bv};
#pragma unroll
        for (int mt = 0; mt < 4; ++mt) facc[mt][nt] = f0;
    }
    g1f<0, false>(W1p, b1r, Yb, nullptr, w, lane, q, cbit, c7, g, th);
    tanh_pack(g, th);  // c0
    g1f<1, true>(W1p, b1r, Yb, Hc0, w, lane, q, cbit, c7, g, th);  // scat c0
    tanh_pack(g, th);  // c1
    __syncthreads();   // Hc0(c0) ready
    g2f<0, true>(W2p, Hc0, Hc1, w, lane, q, cbit, c7, facc, th);  // scat c1
    g1f<2, false>(W1p, b1r, Yb, nullptr, w, lane, q, cbit, c7, g, th);
    tanh_pack(g, th);  // c2
    __syncthreads();   // Hc1(c1) ready
    g2f<1, true>(W2p, Hc1, Hc0, w, lane, q, cbit, c7, facc, th);  // scat c2
    g1f<3, false>(W1p, b1r, Yb, nullptr, w, lane, q, cbit, c7, g, th);
    tanh_pack(g, th);  // c3
    __syncthreads();   // Hc0(c2) ready
    g2f<2, true>(W2p, Hc0, Hc1, w, lane, q, cbit, c7, facc, th);  // scat c3
    __syncthreads();   // Hc1(c3) ready
    g2f<3, false>(W2p, Hc1, nullptr, w, lane, q, cbit, c7, facc, th);
}

__global__ __launch_bounds__(256, 2) void theta_main(
    const float* __restrict__ x,
    const float* __restrict__ b1,
    const float* __restrict__ b2,
    const short* __restrict__ W1p,
    const short* __restrict__ W2p,
    float* __restrict__ out) {
    __shared__ __align__(16) short Yb[16384];  // 64r x 256k A-frags, 32 KB
    __shared__ __align__(16) short Hc0[8192];  // 64r x 128k chunk, 16 KB
    __shared__ __align__(16) short Hc1[8192];  // double buffer, 16 KB

    const int tid = threadIdx.x;
    const int w = tid >> 6;
    const int lane = tid & 63;
    const int q = lane >> 4, c = lane & 15;
    const int cbit = c >> 3, c7 = c & 7;
    const int row0 = blockIdx.x << 6;
    const float HT = 0.0625f;  // h*theta == h*(1-theta)

    float b1r[8], b2r[4];
#pragma unroll
    for (int k = 0; k < 8; ++k) b1r[k] = b1[128 * (k >> 1) + 32 * w + 16 * (k & 1) + c];
#pragma unroll
    for (int nt = 0; nt < 4; ++nt) b2r[nt] = b2[64 * w + 16 * nt + c];

    // y state fp32, C-layout. Wave w owns cols [64w, 64w+64).
    float yv[4][4][4];
#pragma unroll
    for (int mt = 0; mt < 4; ++mt)
#pragma unroll
        for (int nt = 0; nt < 4; ++nt)
#pragma unroll
            for (int r = 0; r < 4; ++r)
                yv[mt][nt][r] = x[(row0 + 16 * mt + 4 * q + r) * 256 + 64 * w + 16 * nt + c];

    // initial Yb = bf16(x) in A-frag layout; wave w fills m-tile w
#pragma unroll
    for (int s = 0; s < 8; ++s) {
        short8 v;
#pragma unroll
        for (int j = 0; j < 8; ++j)
            v[j] = f2bf(x[(row0 + 16 * w + c) * 256 + 32 * s + 8 * q + j]);
        *reinterpret_cast<short8*>(&Yb[((w * 8 + s) * 64 + lane) * 8]) = v;
    }
    __syncthreads();

    floatx4 facc[4][4];

#pragma unroll 1
    for (int step = 0; step < 8; ++step) {
#pragma unroll 1
        for (int it = 0; it < 20; ++it) {
            eval_f(W1p, W2p, b1r, b2r, Yb, Hc0, Hc1, w, lane, q, cbit, c7, facc);
            const bool upd = (it == 0) || (it == 19);   // expl update / final y
            const bool last = (it == 19);
            const bool fin = last && (step == 7);
#pragma unroll
            for (int mt = 0; mt < 4; ++mt)
#pragma unroll
                for (int nt = 0; nt < 4; ++nt) {
                    int kst = 2 * w + (nt >> 1);
                    int lp = 4 * q + 16 * ((2 * nt + cbit) & 3);
                    short* dst = &Yb[((mt * 8 + kst) * 64 + lp) * 8 + c7];
#pragma unroll
                    for (int r = 0; r < 4; ++r) {
                        float fv = facc[mt][nt][r];
                        if (upd) yv[mt][nt][r] += HT * fv;
                        float z = last ? yv[mt][nt][r] : yv[mt][nt][r] + HT * fv;
                        if (fin) {
                            out[(row0 + 16 * mt + 4 * q + r) * 256 + 64 * w + 16 * nt + c] = z;
                        } else {
                            dst[8 * r] = f2bf(z);
                        }
                    }
                }
            __syncthreads();
        }
    }
}

extern "C" void kernel_launch(void* const* d_in, const int* in_sizes, int n_in,
                              void* d_out, int out_size, void* d_ws, size_t ws_size,
                              hipStream_t stream) {
    const float* x = (const float*)d_in[0];
    const float* W1 = (const float*)d_in[1];
    const float* b1 = (const float*)d_in[2];
    const float* W2 = (const float*)d_in[3];
    const float* b2 = (const float*)d_in[4];
    float* out = (float*)d_out;

    short* W1p = (short*)d_ws;            // 256*512 bf16 = 256 KB
    short* W2p = W1p + 256 * 512;         // 512*256 bf16 = 256 KB

    repack_weights<<<dim3(128), dim3(256), 0, stream>>>(W1, W2, W1p, W2p);
    theta_main<<<dim3(1024), dim3(256), 0, stream>>>(x, b1, b2, W1p, W2p, out);
}